// Round 1
// 603.314 us; speedup vs baseline: 1.0744x; 1.0744x over previous
//
#include <hip/hip_runtime.h>
#include <cstdint>
#include <cstddef>

#define BM 128
#define BN 128
#define BK 64

typedef float f32x4 __attribute__((ext_vector_type(4)));
typedef __bf16 bf16x8 __attribute__((ext_vector_type(8)));

__device__ __forceinline__ unsigned short f2bf(float f) {
    unsigned int u = __float_as_uint(f);
    u += 0x7fffu + ((u >> 16) & 1u);   // round-to-nearest-even
    return (unsigned short)(u >> 16);
}

__device__ __forceinline__ void async_copy16(const void* g, void* l) {
    __builtin_amdgcn_global_load_lds(
        (__attribute__((address_space(1))) void*)(g),
        (__attribute__((address_space(3))) void*)(l), 16, 0, 0);
}

// ---------------- elementwise prep kernels ----------------

__global__ void cast_x_kernel(const float* __restrict__ x,
                              unsigned short* __restrict__ o, int n8) {
    int i = blockIdx.x * blockDim.x + threadIdx.x;
    if (i >= n8) return;
    const float4* xv = (const float4*)x;
    float4 a = xv[2 * (size_t)i];
    float4 b = xv[2 * (size_t)i + 1];
    union { unsigned short u[8]; uint4 v; } r;
    r.u[0] = f2bf(a.x); r.u[1] = f2bf(a.y); r.u[2] = f2bf(a.z); r.u[3] = f2bf(a.w);
    r.u[4] = f2bf(b.x); r.u[5] = f2bf(b.y); r.u[6] = f2bf(b.z); r.u[7] = f2bf(b.w);
    ((uint4*)o)[i] = r.v;
}

__global__ void dequant_kernel(const int* __restrict__ v,
                               const float* __restrict__ s,
                               unsigned short* __restrict__ o,
                               int colshift, int gpr, int n8) {
    int i = blockIdx.x * blockDim.x + threadIdx.x;
    if (i >= n8) return;
    int e = i * 8;
    int row = e >> colshift;
    int col = e & ((1 << colshift) - 1);
    float sc = s[row * gpr + (col >> 7)];
    int4 a = ((const int4*)v)[2 * (size_t)i];
    int4 b = ((const int4*)v)[2 * (size_t)i + 1];
    union { unsigned short u[8]; uint4 x; } r;
    r.u[0] = f2bf(a.x * sc); r.u[1] = f2bf(a.y * sc);
    r.u[2] = f2bf(a.z * sc); r.u[3] = f2bf(a.w * sc);
    r.u[4] = f2bf(b.x * sc); r.u[5] = f2bf(b.y * sc);
    r.u[6] = f2bf(b.z * sc); r.u[7] = f2bf(b.w * sc);
    ((uint4*)o)[i] = r.x;
}

// ---------------- GEMM (128x128, m97-structure): kept for gemm1 ----------------
__global__ void __launch_bounds__(256)
gemm_bt_kernel(const __bf16* __restrict__ A1, int lda1, int k1steps,
               const __bf16* __restrict__ B1,
               const __bf16* __restrict__ A2, int lda2, int k2steps,
               const __bf16* __restrict__ B2,
               const float* __restrict__ bias,
               float* __restrict__ outf,
               unsigned short* __restrict__ outb,
               int ldo) {
    __shared__ __bf16 As[BM * BK];   // 16 KB
    __shared__ __bf16 Bs[BN * BK];   // 16 KB

    const int tid  = threadIdx.x;
    const int lane = tid & 63;
    const int wave = tid >> 6;
    const int wm = (wave >> 1) * 64;
    const int wn = (wave & 1) * 64;
    const int mBase = blockIdx.y * BM;
    const int nBase = blockIdx.x * BN;
    const int lrow = lane >> 3;
    const int lcol = (((lane & 7) ^ lrow) & 7) * 8;

    f32x4 acc[4][4] = {};

    #pragma unroll 1
    for (int phase = 0; phase < 2; ++phase) {
        const __bf16* A = phase ? A2 : A1;
        const __bf16* B = phase ? B2 : B1;
        const int lda    = phase ? lda2 : lda1;
        const int ksteps = phase ? k2steps : k1steps;

        for (int kt = 0; kt < ksteps; ++kt) {
            const int k0 = kt * BK;
            #pragma unroll
            for (int r = 0; r < 4; ++r) {
                const int chunk = wave * 4 + r;
                const int row = chunk * 8 + lrow;
                async_copy16(A + (size_t)(mBase + row) * lda + (k0 + lcol),
                             &As[chunk * 512]);
                async_copy16(B + (size_t)(nBase + row) * lda + (k0 + lcol),
                             &Bs[chunk * 512]);
            }
            __syncthreads();

            #pragma unroll
            for (int ks = 0; ks < 2; ++ks) {
                const int kofs = ks * 32 + (lane >> 4) * 8;
                const int swz = kofs >> 3;
                bf16x8 af[4], bfr[4];
                #pragma unroll
                for (int i = 0; i < 4; ++i) {
                    const int m = wm + i * 16 + (lane & 15);
                    af[i] = *(const bf16x8*)&As[m * BK + (((swz ^ m) & 7) << 3)];
                }
                #pragma unroll
                for (int j = 0; j < 4; ++j) {
                    const int n = wn + j * 16 + (lane & 15);
                    bfr[j] = *(const bf16x8*)&Bs[n * BK + (((swz ^ n) & 7) << 3)];
                }
                #pragma unroll
                for (int i = 0; i < 4; ++i)
                    #pragma unroll
                    for (int j = 0; j < 4; ++j)
                        acc[i][j] = __builtin_amdgcn_mfma_f32_16x16x32_bf16(
                            af[i], bfr[j], acc[i][j], 0, 0, 0);
            }
            __syncthreads();
        }
    }

    const int cn = lane & 15;
    const int rg = (lane >> 4) * 4;
    if (outf) {
        #pragma unroll
        for (int j = 0; j < 4; ++j) {
            const int o = nBase + wn + j * 16 + cn;
            const float bv = bias[o];
            #pragma unroll
            for (int i = 0; i < 4; ++i) {
                const int t0 = mBase + wm + i * 16 + rg;
                #pragma unroll
                for (int r = 0; r < 4; ++r)
                    outf[(size_t)(t0 + r) * ldo + o] = acc[i][j][r] + bv;
            }
        }
    } else {
        #pragma unroll
        for (int j = 0; j < 4; ++j) {
            const int o = nBase + wn + j * 16 + cn;
            #pragma unroll
            for (int i = 0; i < 4; ++i) {
                const int t0 = mBase + wm + i * 16 + rg;
                #pragma unroll
                for (int r = 0; r < 4; ++r)
                    outb[(size_t)(t0 + r) * ldo + o] = f2bf(acc[i][j][r]);
            }
        }
    }
}

// ---------------- 256x256 8-phase pipelined GEMM (m201-style template) -------
// out[M,N] = A1*B1^T + A2*B2^T + bias. 512 threads = 8 waves (2M x 4N),
// per-wave 128x64 output -> acc[8][4]. BK=64. LDS = 2 K-tile slots (even->0,
// odd->1) x {A,B} x {half0,half1} x [128x64] bf16 = 128 KiB. Staging runs
// 1.75 K-tiles ahead; counted s_waitcnt vmcnt(6) ONLY at phases 4 and 8
// (never 0 in the loop); raw s_barrier + lgkmcnt(0) per phase; setprio(1)
// around each 16-MFMA cluster. Chunk-XOR LDS swizzle (chunk ^= row&7) is the
// conflict-free scheme carried from the 128^2 kernel (measured 0 conflicts).
//
// Per K-tile phase ledger (stage order [B0,B1,A0,A1] per tile):
//  ph1: read A(mg0)+B(lo) slot0 | stage A1(2i+1)   -> confirmed by ph4 vmcnt
//  ph2: read B(hi)        slot0 | stage B0(2i+2)   (WAR: B0 last read = ph2,
//  ph3: read A(mg1)       slot0 | stage B1(2i+2)    reads issue before stage,
//  ph4: (regs live)             | stage A0(2i+2) + vmcnt(6)  return >=200cy)
//  ph5..8: same on slot1 (tile 2i+1), staging A1(2i+2), B0/B1/A0(2i+3)
// Last iteration clamps prefetch tiles to {nt-2, nt-1} (same slot parity ->
// rewrites identical bytes; fully race-immune). Runs end vmcnt(0)+barrier.

#define SM_OFF(slot_, mat_, half_) ((((slot_) * 2 + (mat_)) * 2 + (half_)) * 8192)

#define MFMA_QUAD(MG, NG, AA, BB)                                           \
    _Pragma("unroll")                                                       \
    for (int m_ = 0; m_ < 4; ++m_)                                          \
        _Pragma("unroll")                                                   \
        for (int n_ = 0; n_ < 2; ++n_)                                      \
            _Pragma("unroll")                                               \
            for (int k_ = 0; k_ < 2; ++k_)                                  \
                acc[(MG)*4 + m_][(NG)*2 + n_] =                             \
                    __builtin_amdgcn_mfma_f32_16x16x32_bf16(                \
                        AA[m_][k_], BB[n_][k_],                             \
                        acc[(MG)*4 + m_][(NG)*2 + n_], 0, 0, 0)

__device__ __forceinline__ void run_pipeline(
    const __bf16* __restrict__ A, const __bf16* __restrict__ B,
    const int lda, const int nt,
    const int mBase, const int nBase,
    const int wave, const int lane, const int wr, const int wc,
    __bf16* smp, f32x4 (&acc)[8][4])
{
    const int lrow  = lane >> 3;
    const int lcol  = (((lane & 7) ^ lrow) & 7) * 8;
    const int soff0 = (wave * 8 + lrow) * lda + lcol;
    const int soff1 = ((wave + 8) * 8 + lrow) * lda + lcol;

    const __bf16* Abase = A + (size_t)mBase * lda;
    const __bf16* Bbase = B + (size_t)nBase * lda;

    const int aoff0 = (lane & 15) * 64 + ((((lane >> 4))     ^ (lane & 7)) * 8);
    const int aoff1 = (lane & 15) * 64 + (((4 + (lane >> 4)) ^ (lane & 7)) * 8);

    const __bf16* Ah0 = smp + SM_OFF(0, 0, wr);
    const __bf16* Ah1 = smp + SM_OFF(1, 0, wr);
    const __bf16* Bh0 = smp + SM_OFF(0, 1, wc >> 1) + (wc & 1) * 4096;
    const __bf16* Bh1 = smp + SM_OFF(1, 1, wc >> 1) + (wc & 1) * 4096;

#define STAGE(base_, half_, tile_, slot_, mat_) do {                         \
        const __bf16* g_ = (base_) + (size_t)((half_) * 128) * lda +         \
                           (size_t)(tile_) * 64;                             \
        __bf16* d_ = smp + SM_OFF(slot_, mat_, half_);                       \
        async_copy16(g_ + soff0, d_ + wave * 512);                           \
        async_copy16(g_ + soff1, d_ + (wave + 8) * 512);                     \
    } while (0)

    // prologue: tile0 [B0,B1,A0,A1], tile1 [B0,B1,A0] = 7 halves (14 loads)
    STAGE(Bbase, 0, 0, 0, 1);
    STAGE(Bbase, 1, 0, 0, 1);
    STAGE(Abase, 0, 0, 0, 0);
    STAGE(Abase, 1, 0, 0, 0);
    STAGE(Bbase, 0, 1, 1, 1);
    STAGE(Bbase, 1, 1, 1, 1);
    STAGE(Abase, 0, 1, 1, 0);
    asm volatile("s_waitcnt vmcnt(6)" ::: "memory");   // tile0 resident
    __builtin_amdgcn_s_barrier();

    bf16x8 aR[4][2], bLo[2][2], bHi[2][2];

    const int niter = nt >> 1;
    #pragma unroll 1
    for (int i = 0; i < niter; ++i) {
        const int t1 = 2 * i + 1;
        int p2 = 2 * i + 2; if (p2 >= nt) p2 = nt - 2;   // even -> slot0
        int p3 = 2 * i + 3; if (p3 >= nt) p3 = nt - 1;   // odd  -> slot1

        // ---- phase 1 ----
        #pragma unroll
        for (int m = 0; m < 4; ++m) {
            aR[m][0] = *(const bf16x8*)(Ah0 + m * 1024 + aoff0);
            aR[m][1] = *(const bf16x8*)(Ah0 + m * 1024 + aoff1);
        }
        #pragma unroll
        for (int n = 0; n < 2; ++n) {
            bLo[n][0] = *(const bf16x8*)(Bh0 + n * 1024 + aoff0);
            bLo[n][1] = *(const bf16x8*)(Bh0 + n * 1024 + aoff1);
        }
        STAGE(Abase, 1, t1, 1, 0);
        __builtin_amdgcn_s_barrier();
        asm volatile("s_waitcnt lgkmcnt(0)" ::: "memory");
        __builtin_amdgcn_s_setprio(1);
        MFMA_QUAD(0, 0, aR, bLo);
        __builtin_amdgcn_s_setprio(0);
        __builtin_amdgcn_s_barrier();

        // ---- phase 2 ----
        #pragma unroll
        for (int n = 0; n < 2; ++n) {
            bHi[n][0] = *(const bf16x8*)(Bh0 + (2 + n) * 1024 + aoff0);
            bHi[n][1] = *(const bf16x8*)(Bh0 + (2 + n) * 1024 + aoff1);
        }
        STAGE(Bbase, 0, p2, 0, 1);
        __builtin_amdgcn_s_barrier();
        asm volatile("s_waitcnt lgkmcnt(0)" ::: "memory");
        __builtin_amdgcn_s_setprio(1);
        MFMA_QUAD(0, 1, aR, bHi);
        __builtin_amdgcn_s_setprio(0);
        __builtin_amdgcn_s_barrier();

        // ---- phase 3 ----
        #pragma unroll
        for (int m = 0; m < 4; ++m) {
            aR[m][0] = *(const bf16x8*)(Ah0 + (4 + m) * 1024 + aoff0);
            aR[m][1] = *(const bf16x8*)(Ah0 + (4 + m) * 1024 + aoff1);
        }
        STAGE(Bbase, 1, p2, 0, 1);
        __builtin_amdgcn_s_barrier();
        asm volatile("s_waitcnt lgkmcnt(0)" ::: "memory");
        __builtin_amdgcn_s_setprio(1);
        MFMA_QUAD(1, 1, aR, bHi);
        __builtin_amdgcn_s_setprio(0);
        __builtin_amdgcn_s_barrier();

        // ---- phase 4 (checkpoint) ----
        STAGE(Abase, 0, p2, 0, 0);
        asm volatile("s_waitcnt vmcnt(6)" ::: "memory");
        __builtin_amdgcn_s_barrier();
        __builtin_amdgcn_s_setprio(1);
        MFMA_QUAD(1, 0, aR, bLo);
        __builtin_amdgcn_s_setprio(0);
        __builtin_amdgcn_s_barrier();

        // ---- phase 5 ----
        #pragma unroll
        for (int m = 0; m < 4; ++m) {
            aR[m][0] = *(const bf16x8*)(Ah1 + m * 1024 + aoff0);
            aR[m][1] = *(const bf16x8*)(Ah1 + m * 1024 + aoff1);
        }
        #pragma unroll
        for (int n = 0; n < 2; ++n) {
            bLo[n][0] = *(const bf16x8*)(Bh1 + n * 1024 + aoff0);
            bLo[n][1] = *(const bf16x8*)(Bh1 + n * 1024 + aoff1);
        }
        STAGE(Abase, 1, p2, 0, 0);
        __builtin_amdgcn_s_barrier();
        asm volatile("s_waitcnt lgkmcnt(0)" ::: "memory");
        __builtin_amdgcn_s_setprio(1);
        MFMA_QUAD(0, 0, aR, bLo);
        __builtin_amdgcn_s_setprio(0);
        __builtin_amdgcn_s_barrier();

        // ---- phase 6 ----
        #pragma unroll
        for (int n = 0; n < 2; ++n) {
            bHi[n][0] = *(const bf16x8*)(Bh1 + (2 + n) * 1024 + aoff0);
            bHi[n][1] = *(const bf16x8*)(Bh1 + (2 + n) * 1024 + aoff1);
        }
        STAGE(Bbase, 0, p3, 1, 1);
        __builtin_amdgcn_s_barrier();
        asm volatile("s_waitcnt lgkmcnt(0)" ::: "memory");
        __builtin_amdgcn_s_setprio(1);
        MFMA_QUAD(0, 1, aR, bHi);
        __builtin_amdgcn_s_setprio(0);
        __builtin_amdgcn_s_barrier();

        // ---- phase 7 ----
        #pragma unroll
        for (int m = 0; m < 4; ++m) {
            aR[m][0] = *(const bf16x8*)(Ah1 + (4 + m) * 1024 + aoff0);
            aR[m][1] = *(const bf16x8*)(Ah1 + (4 + m) * 1024 + aoff1);
        }
        STAGE(Bbase, 1, p3, 1, 1);
        __builtin_amdgcn_s_barrier();
        asm volatile("s_waitcnt lgkmcnt(0)" ::: "memory");
        __builtin_amdgcn_s_setprio(1);
        MFMA_QUAD(1, 1, aR, bHi);
        __builtin_amdgcn_s_setprio(0);
        __builtin_amdgcn_s_barrier();

        // ---- phase 8 (checkpoint) ----
        STAGE(Abase, 0, p3, 1, 0);
        asm volatile("s_waitcnt vmcnt(6)" ::: "memory");
        __builtin_amdgcn_s_barrier();
        __builtin_amdgcn_s_setprio(1);
        MFMA_QUAD(1, 0, aR, bLo);
        __builtin_amdgcn_s_setprio(0);
        __builtin_amdgcn_s_barrier();
    }

    // drain leftover (clamped) prefetches before slots are re-staged / exit
    asm volatile("s_waitcnt vmcnt(0)" ::: "memory");
    __builtin_amdgcn_s_barrier();
#undef STAGE
}

__global__ void __launch_bounds__(512, 2)
gemm256_kernel(const __bf16* __restrict__ A1, const __bf16* __restrict__ B1,
               int lda1, int nt1,
               const __bf16* __restrict__ A2, const __bf16* __restrict__ B2,
               int lda2, int nt2,
               const float* __restrict__ bias, float* __restrict__ out,
               int ldo, int gxlog2) {
    __shared__ __bf16 sm[2][2][2][8192];   // 128 KiB

    const int tid  = threadIdx.x;
    const int lane = tid & 63;
    const int wave = tid >> 6;
    const int wr = wave >> 2;    // 0..1  (M)
    const int wc = wave & 3;     // 0..3  (N)

    // bijective XCD swizzle (grid % 8 == 0)
    const int bid = blockIdx.x;
    const int cpx = gridDim.x >> 3;
    const int s   = (bid & 7) * cpx + (bid >> 3);
    const int bx  = s & ((1 << gxlog2) - 1);
    const int by  = s >> gxlog2;
    const int mBase = by * 256;
    const int nBase = bx * 256;

    f32x4 acc[8][4] = {};

    __bf16* smp = &sm[0][0][0][0];
    run_pipeline(A1, B1, lda1, nt1, mBase, nBase, wave, lane, wr, wc, smp, acc);
    run_pipeline(A2, B2, lda2, nt2, mBase, nBase, wave, lane, wr, wc, smp, acc);

    // epilogue: C/D layout col = lane&15, row = (lane>>4)*4 + reg
    const int cn = lane & 15;
    const int rg = (lane >> 4) * 4;
    const int row0 = mBase + wr * 128 + rg;
    const int col0 = nBase + wc * 64 + cn;
    #pragma unroll
    for (int nf = 0; nf < 4; ++nf) {
        const int o = col0 + nf * 16;
        const float bv = bias[o];
        #pragma unroll
        for (int mf = 0; mf < 8; ++mf) {
            const int t0 = row0 + mf * 16;
            #pragma unroll
            for (int r = 0; r < 4; ++r)
                out[(size_t)(t0 + r) * ldo + o] = acc[mf][nf][r] + bv;
        }
    }
}

extern "C" void kernel_launch(void* const* d_in, const int* in_sizes, int n_in,
                              void* d_out, int out_size, void* d_ws, size_t ws_size,
                              hipStream_t stream) {
    const float* x    = (const float*)d_in[0];
    const int*   qv   = (const int*)d_in[1];
    const float* qs   = (const float*)d_in[2];
    const int*   lv   = (const int*)d_in[3];
    const float* ls   = (const float*)d_in[4];
    const int*   rv   = (const int*)d_in[5];
    const float* rs   = (const float*)d_in[6];
    const float* bias = (const float*)d_in[7];
    float* out = (float*)d_out;

    const int T = 8192, DI = 4096, DO = 4096, R = 256;

    char* ws = (char*)d_ws;
    unsigned short* xb = (unsigned short*)(ws);                    // 8192x4096 bf16 = 64 MiB
    unsigned short* Qd = (unsigned short*)(ws + 67108864);         // 4096x4096 bf16 = 32 MiB
    unsigned short* Rd = (unsigned short*)(ws + 100663296);        //  256x4096 bf16 =  2 MiB
    unsigned short* Ld = (unsigned short*)(ws + 102760448);        // 4096x 256 bf16 =  2 MiB
    unsigned short* xr = (unsigned short*)(ws + 104857600);        // 8192x 256 bf16 =  4 MiB

    {
        int n8 = T * DI / 8;
        cast_x_kernel<<<(n8 + 255) / 256, 256, 0, stream>>>(x, xb, n8);
    }
    {
        int n8 = DO * DI / 8;
        dequant_kernel<<<(n8 + 255) / 256, 256, 0, stream>>>(qv, qs, Qd, 12, DI / 128, n8);
    }
    {
        int n8 = DO * R / 8;
        dequant_kernel<<<(n8 + 255) / 256, 256, 0, stream>>>(lv, ls, Ld, 8, R / 128, n8);
    }
    {
        int n8 = R * DI / 8;
        dequant_kernel<<<(n8 + 255) / 256, 256, 0, stream>>>(rv, rs, Rd, 12, DI / 128, n8);
    }
    {   // gemm1: xr[T,R] = xb @ Rd^T   (N=256 too narrow for 256^2 tile)
        dim3 g(R / BN, T / BM);
        gemm_bt_kernel<<<g, 256, 0, stream>>>(
            (const __bf16*)xb, DI, DI / BK, (const __bf16*)Rd,
            nullptr, 0, 0, nullptr,
            nullptr, nullptr, xr, R);
    }
    {   // gemm2: out[T,DO] = xb @ Qd^T + xr @ Ld^T + bias  (256^2 8-phase)
        int nblocks = (DO / 256) * (T / 256);   // 16 * 32 = 512
        gemm256_kernel<<<nblocks, 512, 0, stream>>>(
            (const __bf16*)xb, (const __bf16*)Qd, DI, DI / 64,
            (const __bf16*)xr, (const __bf16*)Ld, R, R / 64,
            bias, out, DO, 4 /* log2(DO/256) */);
    }
}

// Round 2
// 550.136 us; speedup vs baseline: 1.1783x; 1.0967x over previous
//
#include <hip/hip_runtime.h>
#include <cstdint>
#include <cstddef>

typedef float f32x4 __attribute__((ext_vector_type(4)));
typedef __bf16 bf16x8 __attribute__((ext_vector_type(8)));

__device__ __forceinline__ unsigned short f2bf(float f) {
    unsigned int u = __float_as_uint(f);
    u += 0x7fffu + ((u >> 16) & 1u);   // round-to-nearest-even
    return (unsigned short)(u >> 16);
}

__device__ __forceinline__ void async_copy16(const void* g, void* l) {
    __builtin_amdgcn_global_load_lds(
        (__attribute__((address_space(1))) void*)(g),
        (__attribute__((address_space(3))) void*)(l), 16, 0, 0);
}

// ---------------- elementwise prep kernels ----------------

__global__ void cast_x_kernel(const float* __restrict__ x,
                              unsigned short* __restrict__ o, int n8) {
    int i = blockIdx.x * blockDim.x + threadIdx.x;
    if (i >= n8) return;
    const float4* xv = (const float4*)x;
    float4 a = xv[2 * (size_t)i];
    float4 b = xv[2 * (size_t)i + 1];
    union { unsigned short u[8]; uint4 v; } r;
    r.u[0] = f2bf(a.x); r.u[1] = f2bf(a.y); r.u[2] = f2bf(a.z); r.u[3] = f2bf(a.w);
    r.u[4] = f2bf(b.x); r.u[5] = f2bf(b.y); r.u[6] = f2bf(b.z); r.u[7] = f2bf(b.w);
    ((uint4*)o)[i] = r.v;
}

__global__ void dequant_kernel(const int* __restrict__ v,
                               const float* __restrict__ s,
                               unsigned short* __restrict__ o,
                               int colshift, int gpr, int n8) {
    int i = blockIdx.x * blockDim.x + threadIdx.x;
    if (i >= n8) return;
    int e = i * 8;
    int row = e >> colshift;
    int col = e & ((1 << colshift) - 1);
    float sc = s[row * gpr + (col >> 7)];
    int4 a = ((const int4*)v)[2 * (size_t)i];
    int4 b = ((const int4*)v)[2 * (size_t)i + 1];
    union { unsigned short u[8]; uint4 x; } r;
    r.u[0] = f2bf(a.x * sc); r.u[1] = f2bf(a.y * sc);
    r.u[2] = f2bf(a.z * sc); r.u[3] = f2bf(a.w * sc);
    r.u[4] = f2bf(b.x * sc); r.u[5] = f2bf(b.y * sc);
    r.u[6] = f2bf(b.z * sc); r.u[7] = f2bf(b.w * sc);
    ((uint4*)o)[i] = r.x;
}

// Dequantize R [256][4096] -> transposed Rt [4096][256] bf16.
// Reads coalesced (lanes = consecutive i); writes 16B per thread, stride
// 512B between lanes (L2 absorbs the partial-sector writes; Rt is 2 MiB).
__global__ void rt_dequant_kernel(const int* __restrict__ v,
                                  const float* __restrict__ s,
                                  unsigned short* __restrict__ o) {
    int g = blockIdx.x * blockDim.x + threadIdx.x;   // 0 .. 131071
    int i  = g & 4095;
    int r0 = (g >> 12) << 3;                         // 0,8,...,248
    int grp = i >> 7;
    union { unsigned short u[8]; uint4 x; } w;
    #pragma unroll
    for (int k = 0; k < 8; ++k) {
        int r = r0 + k;
        float sc = s[r * 32 + grp];
        w.u[k] = f2bf((float)v[(size_t)r * 4096 + i] * sc);
    }
    *(uint4*)&o[(size_t)i * 256 + r0] = w.x;
}

// ---------------- 256x256 8-phase pipelined GEMM core ----------------
// (validated round 1 incl. nt=4 clamped-prefetch path; unchanged)

#define SM_OFF(slot_, mat_, half_) ((((slot_) * 2 + (mat_)) * 2 + (half_)) * 8192)

#define MFMA_QUAD(MG, NG, AA, BB)                                           \
    _Pragma("unroll")                                                       \
    for (int m_ = 0; m_ < 4; ++m_)                                          \
        _Pragma("unroll")                                                   \
        for (int n_ = 0; n_ < 2; ++n_)                                      \
            _Pragma("unroll")                                               \
            for (int k_ = 0; k_ < 2; ++k_)                                  \
                acc[(MG)*4 + m_][(NG)*2 + n_] =                             \
                    __builtin_amdgcn_mfma_f32_16x16x32_bf16(                \
                        AA[m_][k_], BB[n_][k_],                             \
                        acc[(MG)*4 + m_][(NG)*2 + n_], 0, 0, 0)

__device__ __forceinline__ void run_pipeline(
    const __bf16* __restrict__ A, const __bf16* __restrict__ B,
    const int lda, const int nt,
    const int mBase, const int nBase,
    const int wave, const int lane, const int wr, const int wc,
    __bf16* smp, f32x4 (&acc)[8][4])
{
    const int lrow  = lane >> 3;
    const int lcol  = (((lane & 7) ^ lrow) & 7) * 8;
    const int soff0 = (wave * 8 + lrow) * lda + lcol;
    const int soff1 = ((wave + 8) * 8 + lrow) * lda + lcol;

    const __bf16* Abase = A + (size_t)mBase * lda;
    const __bf16* Bbase = B + (size_t)nBase * lda;

    const int aoff0 = (lane & 15) * 64 + ((((lane >> 4))     ^ (lane & 7)) * 8);
    const int aoff1 = (lane & 15) * 64 + (((4 + (lane >> 4)) ^ (lane & 7)) * 8);

    const __bf16* Ah0 = smp + SM_OFF(0, 0, wr);
    const __bf16* Ah1 = smp + SM_OFF(1, 0, wr);
    const __bf16* Bh0 = smp + SM_OFF(0, 1, wc >> 1) + (wc & 1) * 4096;
    const __bf16* Bh1 = smp + SM_OFF(1, 1, wc >> 1) + (wc & 1) * 4096;

#define STAGE(base_, half_, tile_, slot_, mat_) do {                         \
        const __bf16* g_ = (base_) + (size_t)((half_) * 128) * lda +         \
                           (size_t)(tile_) * 64;                             \
        __bf16* d_ = smp + SM_OFF(slot_, mat_, half_);                       \
        async_copy16(g_ + soff0, d_ + wave * 512);                           \
        async_copy16(g_ + soff1, d_ + (wave + 8) * 512);                     \
    } while (0)

    // prologue: tile0 [B0,B1,A0,A1], tile1 [B0,B1,A0] = 7 halves (14 loads)
    STAGE(Bbase, 0, 0, 0, 1);
    STAGE(Bbase, 1, 0, 0, 1);
    STAGE(Abase, 0, 0, 0, 0);
    STAGE(Abase, 1, 0, 0, 0);
    STAGE(Bbase, 0, 1, 1, 1);
    STAGE(Bbase, 1, 1, 1, 1);
    STAGE(Abase, 0, 1, 1, 0);
    asm volatile("s_waitcnt vmcnt(6)" ::: "memory");   // tile0 resident
    __builtin_amdgcn_s_barrier();

    bf16x8 aR[4][2], bLo[2][2], bHi[2][2];

    const int niter = nt >> 1;
    #pragma unroll 1
    for (int i = 0; i < niter; ++i) {
        const int t1 = 2 * i + 1;
        int p2 = 2 * i + 2; if (p2 >= nt) p2 = nt - 2;   // even -> slot0
        int p3 = 2 * i + 3; if (p3 >= nt) p3 = nt - 1;   // odd  -> slot1

        // ---- phase 1 ----
        #pragma unroll
        for (int m = 0; m < 4; ++m) {
            aR[m][0] = *(const bf16x8*)(Ah0 + m * 1024 + aoff0);
            aR[m][1] = *(const bf16x8*)(Ah0 + m * 1024 + aoff1);
        }
        #pragma unroll
        for (int n = 0; n < 2; ++n) {
            bLo[n][0] = *(const bf16x8*)(Bh0 + n * 1024 + aoff0);
            bLo[n][1] = *(const bf16x8*)(Bh0 + n * 1024 + aoff1);
        }
        STAGE(Abase, 1, t1, 1, 0);
        __builtin_amdgcn_s_barrier();
        asm volatile("s_waitcnt lgkmcnt(0)" ::: "memory");
        __builtin_amdgcn_s_setprio(1);
        MFMA_QUAD(0, 0, aR, bLo);
        __builtin_amdgcn_s_setprio(0);
        __builtin_amdgcn_s_barrier();

        // ---- phase 2 ----
        #pragma unroll
        for (int n = 0; n < 2; ++n) {
            bHi[n][0] = *(const bf16x8*)(Bh0 + (2 + n) * 1024 + aoff0);
            bHi[n][1] = *(const bf16x8*)(Bh0 + (2 + n) * 1024 + aoff1);
        }
        STAGE(Bbase, 0, p2, 0, 1);
        __builtin_amdgcn_s_barrier();
        asm volatile("s_waitcnt lgkmcnt(0)" ::: "memory");
        __builtin_amdgcn_s_setprio(1);
        MFMA_QUAD(0, 1, aR, bHi);
        __builtin_amdgcn_s_setprio(0);
        __builtin_amdgcn_s_barrier();

        // ---- phase 3 ----
        #pragma unroll
        for (int m = 0; m < 4; ++m) {
            aR[m][0] = *(const bf16x8*)(Ah0 + (4 + m) * 1024 + aoff0);
            aR[m][1] = *(const bf16x8*)(Ah0 + (4 + m) * 1024 + aoff1);
        }
        STAGE(Bbase, 1, p2, 0, 1);
        __builtin_amdgcn_s_barrier();
        asm volatile("s_waitcnt lgkmcnt(0)" ::: "memory");
        __builtin_amdgcn_s_setprio(1);
        MFMA_QUAD(1, 1, aR, bHi);
        __builtin_amdgcn_s_setprio(0);
        __builtin_amdgcn_s_barrier();

        // ---- phase 4 (checkpoint) ----
        STAGE(Abase, 0, p2, 0, 0);
        asm volatile("s_waitcnt vmcnt(6)" ::: "memory");
        __builtin_amdgcn_s_barrier();
        __builtin_amdgcn_s_setprio(1);
        MFMA_QUAD(1, 0, aR, bLo);
        __builtin_amdgcn_s_setprio(0);
        __builtin_amdgcn_s_barrier();

        // ---- phase 5 ----
        #pragma unroll
        for (int m = 0; m < 4; ++m) {
            aR[m][0] = *(const bf16x8*)(Ah1 + m * 1024 + aoff0);
            aR[m][1] = *(const bf16x8*)(Ah1 + m * 1024 + aoff1);
        }
        #pragma unroll
        for (int n = 0; n < 2; ++n) {
            bLo[n][0] = *(const bf16x8*)(Bh1 + n * 1024 + aoff0);
            bLo[n][1] = *(const bf16x8*)(Bh1 + n * 1024 + aoff1);
        }
        STAGE(Abase, 1, p2, 0, 0);
        __builtin_amdgcn_s_barrier();
        asm volatile("s_waitcnt lgkmcnt(0)" ::: "memory");
        __builtin_amdgcn_s_setprio(1);
        MFMA_QUAD(0, 0, aR, bLo);
        __builtin_amdgcn_s_setprio(0);
        __builtin_amdgcn_s_barrier();

        // ---- phase 6 ----
        #pragma unroll
        for (int n = 0; n < 2; ++n) {
            bHi[n][0] = *(const bf16x8*)(Bh1 + (2 + n) * 1024 + aoff0);
            bHi[n][1] = *(const bf16x8*)(Bh1 + (2 + n) * 1024 + aoff1);
        }
        STAGE(Bbase, 0, p3, 1, 1);
        __builtin_amdgcn_s_barrier();
        asm volatile("s_waitcnt lgkmcnt(0)" ::: "memory");
        __builtin_amdgcn_s_setprio(1);
        MFMA_QUAD(0, 1, aR, bHi);
        __builtin_amdgcn_s_setprio(0);
        __builtin_amdgcn_s_barrier();

        // ---- phase 7 ----
        #pragma unroll
        for (int m = 0; m < 4; ++m) {
            aR[m][0] = *(const bf16x8*)(Ah1 + (4 + m) * 1024 + aoff0);
            aR[m][1] = *(const bf16x8*)(Ah1 + (4 + m) * 1024 + aoff1);
        }
        STAGE(Bbase, 1, p3, 1, 1);
        __builtin_amdgcn_s_barrier();
        asm volatile("s_waitcnt lgkmcnt(0)" ::: "memory");
        __builtin_amdgcn_s_setprio(1);
        MFMA_QUAD(1, 1, aR, bHi);
        __builtin_amdgcn_s_setprio(0);
        __builtin_amdgcn_s_barrier();

        // ---- phase 8 (checkpoint) ----
        STAGE(Abase, 0, p3, 1, 0);
        asm volatile("s_waitcnt vmcnt(6)" ::: "memory");
        __builtin_amdgcn_s_barrier();
        __builtin_amdgcn_s_setprio(1);
        MFMA_QUAD(1, 0, aR, bLo);
        __builtin_amdgcn_s_setprio(0);
        __builtin_amdgcn_s_barrier();
    }

    asm volatile("s_waitcnt vmcnt(0)" ::: "memory");
    __builtin_amdgcn_s_barrier();
#undef STAGE
}

// ---------------- W' builder: W'[o,i] = q[o,i]*qs + sum_r Ld[o,r]*Rt[i,r] ----
// 256x256 tile, K=256 (nt=4). Epilogue: LDS-transpose (two fp32 64-row
// halves, bank-XOR on col bit4 by row-quarter parity -> 2-way free) then
// coalesced fused dequant: read qv uint4x2, add, write W' bf16 uint4.
__global__ void __launch_bounds__(512, 2)
lr_w_kernel(const __bf16* __restrict__ Ld,   // [4096][256]
            const __bf16* __restrict__ Rt,   // [4096][256]
            const int*   __restrict__ qv,    // [4096][4096]
            const float* __restrict__ qs,    // [4096][32]
            unsigned short* __restrict__ Wp) // [4096][4096] bf16
{
    __shared__ __bf16 sm[2][2][2][8192];   // 128 KiB
    const int tid  = threadIdx.x;
    const int lane = tid & 63;
    const int wave = tid >> 6;
    const int wr = wave >> 2;
    const int wc = wave & 3;

    const int bid = blockIdx.x;
    const int cpx = gridDim.x >> 3;
    const int s   = (bid & 7) * cpx + (bid >> 3);
    const int mBase = (s >> 4) * 256;   // o
    const int nBase = (s & 15) * 256;   // i

    f32x4 acc[8][4] = {};
    __bf16* smp = &sm[0][0][0][0];
    run_pipeline(Ld, Rt, 256, 4, mBase, nBase, wave, lane, wr, wc, smp, acc);

    float* lsm = (float*)smp;            // [128][256] fp32 view
    const int cn = lane & 15;
    const int rg = (lane >> 4) * 4;

    #pragma unroll 1
    for (int h = 0; h < 2; ++h) {
        #pragma unroll
        for (int mf4 = 0; mf4 < 4; ++mf4) {
            const int mf = h * 4 + mf4;
            #pragma unroll
            for (int nf = 0; nf < 4; ++nf) {
                #pragma unroll
                for (int r = 0; r < 4; ++r) {
                    const int lrowi = wr * 64 + mf4 * 16 + rg + r;
                    const int col = (wc * 64 + nf * 16 + cn) ^ (((lrowi >> 2) & 1) << 4);
                    lsm[lrowi * 256 + col] = acc[mf][nf][r];
                }
            }
        }
        __syncthreads();
        #pragma unroll 2
        for (int it = 0; it < 8; ++it) {
            const int linear = it * 512 + tid;       // 0..4095
            const int lrowi  = linear >> 5;          // 0..127
            const int coff   = (linear & 31) * 8;
            const int grow = mBase + ((lrowi >> 6) * 128) + h * 64 + (lrowi & 63);
            const int gcol = nBase + coff;
            const int cswz = (coff * 4) ^ (((lrowi >> 2) & 1) << 6);
            const float* lp = (const float*)((const char*)lsm + (size_t)lrowi * 1024 + cswz);
            f32x4 lo = *(const f32x4*)lp;
            f32x4 hi = *(const f32x4*)(lp + 4);
            const float sc = qs[grow * 32 + (gcol >> 7)];
            const int4 qa = *(const int4*)&qv[(size_t)grow * 4096 + gcol];
            const int4 qb = *(const int4*)&qv[(size_t)grow * 4096 + gcol + 4];
            union { unsigned short u[8]; uint4 x; } w;
            w.u[0] = f2bf(qa.x * sc + lo[0]);
            w.u[1] = f2bf(qa.y * sc + lo[1]);
            w.u[2] = f2bf(qa.z * sc + lo[2]);
            w.u[3] = f2bf(qa.w * sc + lo[3]);
            w.u[4] = f2bf(qb.x * sc + hi[0]);
            w.u[5] = f2bf(qb.y * sc + hi[1]);
            w.u[6] = f2bf(qb.z * sc + hi[2]);
            w.u[7] = f2bf(qb.w * sc + hi[3]);
            *(uint4*)&Wp[(size_t)grow * 4096 + gcol] = w.x;
        }
        __syncthreads();
    }
}

// ---------------- main GEMM: out[T,DO] = xb @ Wp^T + bias ----------------
__global__ void __launch_bounds__(512, 2)
gemm256_kernel(const __bf16* __restrict__ A, const __bf16* __restrict__ B,
               int lda, int nt,
               const float* __restrict__ bias, float* __restrict__ out,
               int ldo, int gxlog2) {
    __shared__ __bf16 sm[2][2][2][8192];   // 128 KiB

    const int tid  = threadIdx.x;
    const int lane = tid & 63;
    const int wave = tid >> 6;
    const int wr = wave >> 2;
    const int wc = wave & 3;

    const int bid = blockIdx.x;
    const int cpx = gridDim.x >> 3;
    const int s   = (bid & 7) * cpx + (bid >> 3);
    const int bx  = s & ((1 << gxlog2) - 1);
    const int by  = s >> gxlog2;
    const int mBase = by * 256;
    const int nBase = bx * 256;

    f32x4 acc[8][4] = {};
    __bf16* smp = &sm[0][0][0][0];
    run_pipeline(A, B, lda, nt, mBase, nBase, wave, lane, wr, wc, smp, acc);

    // epilogue: C/D layout col = lane&15, row = (lane>>4)*4 + reg
    const int cn = lane & 15;
    const int rg = (lane >> 4) * 4;
    const int row0 = mBase + wr * 128 + rg;
    const int col0 = nBase + wc * 64 + cn;
    #pragma unroll
    for (int nf = 0; nf < 4; ++nf) {
        const int o = col0 + nf * 16;
        const float bv = bias[o];
        #pragma unroll
        for (int mf = 0; mf < 8; ++mf) {
            const int t0 = row0 + mf * 16;
            #pragma unroll
            for (int r = 0; r < 4; ++r)
                out[(size_t)(t0 + r) * ldo + o] = acc[mf][nf][r] + bv;
        }
    }
}

extern "C" void kernel_launch(void* const* d_in, const int* in_sizes, int n_in,
                              void* d_out, int out_size, void* d_ws, size_t ws_size,
                              hipStream_t stream) {
    const float* x    = (const float*)d_in[0];
    const int*   qv   = (const int*)d_in[1];
    const float* qs   = (const float*)d_in[2];
    const int*   lv   = (const int*)d_in[3];
    const float* ls   = (const float*)d_in[4];
    const int*   rv   = (const int*)d_in[5];
    const float* rs   = (const float*)d_in[6];
    const float* bias = (const float*)d_in[7];
    float* out = (float*)d_out;

    const int T = 8192, DI = 4096, DO = 4096, R = 256;

    char* ws = (char*)d_ws;
    unsigned short* xb = (unsigned short*)(ws);                 // 8192x4096 bf16 = 64 MiB
    unsigned short* Wp = (unsigned short*)(ws + 67108864);      // 4096x4096 bf16 = 32 MiB
    unsigned short* Ld = (unsigned short*)(ws + 100663296);     // 4096x 256 bf16 =  2 MiB
    unsigned short* Rt = (unsigned short*)(ws + 102760448);     // 4096x 256 bf16 =  2 MiB

    {   // x fp32 -> bf16
        int n8 = T * DI / 8;
        cast_x_kernel<<<(n8 + 255) / 256, 256, 0, stream>>>(x, xb, n8);
    }
    {   // L dequant -> Ld [DO, R]
        int n8 = DO * R / 8;
        dequant_kernel<<<(n8 + 255) / 256, 256, 0, stream>>>(lv, ls, Ld, 8, R / 128, n8);
    }
    {   // R dequant + transpose -> Rt [DI, R]
        rt_dequant_kernel<<<512, 256, 0, stream>>>(rv, rs, Rt);
    }
    {   // Wp = Q*scale + Ld @ Rt^T   (fused dequant epilogue)
        lr_w_kernel<<<256, 512, 0, stream>>>(
            (const __bf16*)Ld, (const __bf16*)Rt, qv, qs, Wp);
    }
    {   // out = xb @ Wp^T + bias
        int nblocks = (DO / 256) * (T / 256);   // 512
        gemm256_kernel<<<nblocks, 512, 0, stream>>>(
            (const __bf16*)xb, (const __bf16*)Wp, DI, DI / 64,
            bias, out, DO, 4 /* log2(DO/256) */);
    }
}

// Round 3
// 541.165 us; speedup vs baseline: 1.1978x; 1.0166x over previous
//
#include <hip/hip_runtime.h>
#include <cstdint>
#include <cstddef>

typedef float f32x4 __attribute__((ext_vector_type(4)));
typedef __bf16 bf16x8 __attribute__((ext_vector_type(8)));

__device__ __forceinline__ unsigned short f2bf(float f) {
    unsigned int u = __float_as_uint(f);
    u += 0x7fffu + ((u >> 16) & 1u);   // round-to-nearest-even
    return (unsigned short)(u >> 16);
}

__device__ __forceinline__ void async_copy16(const void* g, void* l) {
    __builtin_amdgcn_global_load_lds(
        (__attribute__((address_space(1))) void*)(g),
        (__attribute__((address_space(3))) void*)(l), 16, 0, 0);
}

// ---------------- fused prep kernel ----------------
// blocks [0,16384): cast x fp32->bf16 (8192x4096)
// blocks [16384,16896): dequant L -> Ld [4096][256]
// blocks [16896,17408): dequant R + transpose -> Rt [4096][256]
__global__ void prep_kernel(const float* __restrict__ x,
                            unsigned short* __restrict__ xb,
                            const int* __restrict__ lv,
                            const float* __restrict__ ls,
                            unsigned short* __restrict__ Ld,
                            const int* __restrict__ rv,
                            const float* __restrict__ rs,
                            unsigned short* __restrict__ Rt) {
    const int bid = blockIdx.x;
    const int tid = threadIdx.x;
    if (bid < 16384) {
        // cast: n8 = 4194304
        const int i = bid * 256 + tid;
        const float4* xv = (const float4*)x;
        float4 a = xv[2 * (size_t)i];
        float4 b = xv[2 * (size_t)i + 1];
        union { unsigned short u[8]; uint4 v; } r;
        r.u[0] = f2bf(a.x); r.u[1] = f2bf(a.y); r.u[2] = f2bf(a.z); r.u[3] = f2bf(a.w);
        r.u[4] = f2bf(b.x); r.u[5] = f2bf(b.y); r.u[6] = f2bf(b.z); r.u[7] = f2bf(b.w);
        ((uint4*)xb)[i] = r.v;
    } else if (bid < 16896) {
        // dequant L: [4096][256] int -> bf16, group 128 (colshift 8, gpr 2)
        const int i = (bid - 16384) * 256 + tid;     // 0..131071
        const int e = i * 8;
        const int row = e >> 8;
        const int col = e & 255;
        const float sc = ls[row * 2 + (col >> 7)];
        int4 a = ((const int4*)lv)[2 * (size_t)i];
        int4 b = ((const int4*)lv)[2 * (size_t)i + 1];
        union { unsigned short u[8]; uint4 v; } r;
        r.u[0] = f2bf(a.x * sc); r.u[1] = f2bf(a.y * sc);
        r.u[2] = f2bf(a.z * sc); r.u[3] = f2bf(a.w * sc);
        r.u[4] = f2bf(b.x * sc); r.u[5] = f2bf(b.y * sc);
        r.u[6] = f2bf(b.z * sc); r.u[7] = f2bf(b.w * sc);
        ((uint4*)Ld)[i] = r.v;
    } else {
        // R dequant + transpose: Rt[i][r] = rv[r][i]*sc
        const int g = (bid - 16896) * 256 + tid;     // 0..131071
        const int i  = g & 4095;
        const int r0 = (g >> 12) << 3;               // 0,8,...,248
        const int grp = i >> 7;
        union { unsigned short u[8]; uint4 v; } w;
        #pragma unroll
        for (int k = 0; k < 8; ++k) {
            const int r = r0 + k;
            const float sc = rs[r * 32 + grp];
            w.u[k] = f2bf((float)rv[(size_t)r * 4096 + i] * sc);
        }
        *(uint4*)&Rt[(size_t)i * 256 + r0] = w.v;
    }
}

// ---------------- 256x256 8-phase pipelined GEMM core ----------------
// Round-3 revision: ONE barrier per phase ([reads][STAGE][bar][lgkmcnt(0)]
// [setprio/MFMA]) instead of two. vmcnt ledger unchanged (14 outstanding at
// each ph4/ph8 checkpoint, vmcnt(6) retires exactly the 8 loads of the tile
// read next). WAR: every overwriting STAGE still issues >=1 barrier after the
// victim reads issued, + >=200cy DMA-return margin (same margin the template
// already uses for same-phase read-then-stage). Staging addresses hoisted to
// 4 per-lane base pointers + uniform scalar offsets.

#define SM_OFF(slot_, mat_, half_) ((((slot_) * 2 + (mat_)) * 2 + (half_)) * 8192)

#define MFMA_QUAD(MG, NG, AA, BB)                                           \
    _Pragma("unroll")                                                       \
    for (int m_ = 0; m_ < 4; ++m_)                                          \
        _Pragma("unroll")                                                   \
        for (int n_ = 0; n_ < 2; ++n_)                                      \
            _Pragma("unroll")                                               \
            for (int k_ = 0; k_ < 2; ++k_)                                  \
                acc[(MG)*4 + m_][(NG)*2 + n_] =                             \
                    __builtin_amdgcn_mfma_f32_16x16x32_bf16(                \
                        AA[m_][k_], BB[n_][k_],                             \
                        acc[(MG)*4 + m_][(NG)*2 + n_], 0, 0, 0)

#define PH_SYNC()                                                            \
    __builtin_amdgcn_s_barrier();                                            \
    asm volatile("s_waitcnt lgkmcnt(0)" ::: "memory")

__device__ __forceinline__ void run_pipeline(
    const __bf16* __restrict__ A, const __bf16* __restrict__ B,
    const int lda, const int nt,
    const int mBase, const int nBase,
    const int wave, const int lane, const int wr, const int wc,
    __bf16* smp, f32x4 (&acc)[8][4])
{
    const int lrow  = lane >> 3;
    const int lcol  = (((lane & 7) ^ lrow) & 7) * 8;
    const int soff0 = (wave * 8 + lrow) * lda + lcol;
    const size_t dsoff = (size_t)64 * lda;           // second-load lane delta

    // per-lane staging base pointers (loop-invariant)
    const __bf16* gA0 = A + (size_t)mBase * lda + soff0;
    const __bf16* gA1 = gA0 + (size_t)128 * lda;
    const __bf16* gB0 = B + (size_t)nBase * lda + soff0;
    const __bf16* gB1 = gB0 + (size_t)128 * lda;

    const int aoff0 = (lane & 15) * 64 + ((((lane >> 4))     ^ (lane & 7)) * 8);
    const int aoff1 = (lane & 15) * 64 + (((4 + (lane >> 4)) ^ (lane & 7)) * 8);

    const __bf16* Ah0 = smp + SM_OFF(0, 0, wr);
    const __bf16* Ah1 = smp + SM_OFF(1, 0, wr);
    const __bf16* Bh0 = smp + SM_OFF(0, 1, wc >> 1) + (wc & 1) * 4096;
    const __bf16* Bh1 = smp + SM_OFF(1, 1, wc >> 1) + (wc & 1) * 4096;

#define STAGE(gp_, tile_, slot_, mat_, half_) do {                           \
        const __bf16* g_ = (gp_) + (size_t)(tile_) * 64;                     \
        __bf16* d_ = smp + SM_OFF(slot_, mat_, half_);                       \
        async_copy16(g_,         d_ + wave * 512);                           \
        async_copy16(g_ + dsoff, d_ + (wave + 8) * 512);                     \
    } while (0)

    // prologue: tile0 [B0,B1,A0,A1], tile1 [B0,B1,A0] = 7 halves (14 loads)
    STAGE(gB0, 0, 0, 1, 0);
    STAGE(gB1, 0, 0, 1, 1);
    STAGE(gA0, 0, 0, 0, 0);
    STAGE(gA1, 0, 0, 0, 1);
    STAGE(gB0, 1, 1, 1, 0);
    STAGE(gB1, 1, 1, 1, 1);
    STAGE(gA0, 1, 1, 0, 0);
    asm volatile("s_waitcnt vmcnt(6)" ::: "memory");   // tile0 resident
    __builtin_amdgcn_s_barrier();

    bf16x8 aR[4][2], bLo[2][2], bHi[2][2];

    const int niter = nt >> 1;
    #pragma unroll 1
    for (int i = 0; i < niter; ++i) {
        const int t1 = 2 * i + 1;
        int p2 = 2 * i + 2; if (p2 >= nt) p2 = nt - 2;   // even -> slot0
        int p3 = 2 * i + 3; if (p3 >= nt) p3 = nt - 1;   // odd  -> slot1

        // ---- phase 1 ----
        #pragma unroll
        for (int m = 0; m < 4; ++m) {
            aR[m][0] = *(const bf16x8*)(Ah0 + m * 1024 + aoff0);
            aR[m][1] = *(const bf16x8*)(Ah0 + m * 1024 + aoff1);
        }
        #pragma unroll
        for (int n = 0; n < 2; ++n) {
            bLo[n][0] = *(const bf16x8*)(Bh0 + n * 1024 + aoff0);
            bLo[n][1] = *(const bf16x8*)(Bh0 + n * 1024 + aoff1);
        }
        STAGE(gA1, t1, 1, 0, 1);
        PH_SYNC();
        __builtin_amdgcn_s_setprio(1);
        MFMA_QUAD(0, 0, aR, bLo);
        __builtin_amdgcn_s_setprio(0);

        // ---- phase 2 ----
        #pragma unroll
        for (int n = 0; n < 2; ++n) {
            bHi[n][0] = *(const bf16x8*)(Bh0 + (2 + n) * 1024 + aoff0);
            bHi[n][1] = *(const bf16x8*)(Bh0 + (2 + n) * 1024 + aoff1);
        }
        STAGE(gB0, p2, 0, 1, 0);
        PH_SYNC();
        __builtin_amdgcn_s_setprio(1);
        MFMA_QUAD(0, 1, aR, bHi);
        __builtin_amdgcn_s_setprio(0);

        // ---- phase 3 ----
        #pragma unroll
        for (int m = 0; m < 4; ++m) {
            aR[m][0] = *(const bf16x8*)(Ah0 + (4 + m) * 1024 + aoff0);
            aR[m][1] = *(const bf16x8*)(Ah0 + (4 + m) * 1024 + aoff1);
        }
        STAGE(gB1, p2, 0, 1, 1);
        PH_SYNC();
        __builtin_amdgcn_s_setprio(1);
        MFMA_QUAD(1, 1, aR, bHi);
        __builtin_amdgcn_s_setprio(0);

        // ---- phase 4 (checkpoint) ----
        STAGE(gA0, p2, 0, 0, 0);
        asm volatile("s_waitcnt vmcnt(6)" ::: "memory");
        __builtin_amdgcn_s_barrier();
        __builtin_amdgcn_s_setprio(1);
        MFMA_QUAD(1, 0, aR, bLo);
        __builtin_amdgcn_s_setprio(0);

        // ---- phase 5 ----
        #pragma unroll
        for (int m = 0; m < 4; ++m) {
            aR[m][0] = *(const bf16x8*)(Ah1 + m * 1024 + aoff0);
            aR[m][1] = *(const bf16x8*)(Ah1 + m * 1024 + aoff1);
        }
        #pragma unroll
        for (int n = 0; n < 2; ++n) {
            bLo[n][0] = *(const bf16x8*)(Bh1 + n * 1024 + aoff0);
            bLo[n][1] = *(const bf16x8*)(Bh1 + n * 1024 + aoff1);
        }
        STAGE(gA1, p2, 0, 0, 1);
        PH_SYNC();
        __builtin_amdgcn_s_setprio(1);
        MFMA_QUAD(0, 0, aR, bLo);
        __builtin_amdgcn_s_setprio(0);

        // ---- phase 6 ----
        #pragma unroll
        for (int n = 0; n < 2; ++n) {
            bHi[n][0] = *(const bf16x8*)(Bh1 + (2 + n) * 1024 + aoff0);
            bHi[n][1] = *(const bf16x8*)(Bh1 + (2 + n) * 1024 + aoff1);
        }
        STAGE(gB0, p3, 1, 1, 0);
        PH_SYNC();
        __builtin_amdgcn_s_setprio(1);
        MFMA_QUAD(0, 1, aR, bHi);
        __builtin_amdgcn_s_setprio(0);

        // ---- phase 7 ----
        #pragma unroll
        for (int m = 0; m < 4; ++m) {
            aR[m][0] = *(const bf16x8*)(Ah1 + (4 + m) * 1024 + aoff0);
            aR[m][1] = *(const bf16x8*)(Ah1 + (4 + m) * 1024 + aoff1);
        }
        STAGE(gB1, p3, 1, 1, 1);
        PH_SYNC();
        __builtin_amdgcn_s_setprio(1);
        MFMA_QUAD(1, 1, aR, bHi);
        __builtin_amdgcn_s_setprio(0);

        // ---- phase 8 (checkpoint) ----
        STAGE(gA0, p3, 1, 0, 0);
        asm volatile("s_waitcnt vmcnt(6)" ::: "memory");
        __builtin_amdgcn_s_barrier();
        __builtin_amdgcn_s_setprio(1);
        MFMA_QUAD(1, 0, aR, bLo);
        __builtin_amdgcn_s_setprio(0);
    }

    asm volatile("s_waitcnt vmcnt(0)" ::: "memory");
    __builtin_amdgcn_s_barrier();
#undef STAGE
}

// ---------------- W' builder: W'[o,i] = q[o,i]*qs + sum_r Ld[o,r]*Rt[i,r] ----
__global__ void __launch_bounds__(512, 2)
lr_w_kernel(const __bf16* __restrict__ Ld,   // [4096][256]
            const __bf16* __restrict__ Rt,   // [4096][256]
            const int*   __restrict__ qv,    // [4096][4096]
            const float* __restrict__ qs,    // [4096][32]
            unsigned short* __restrict__ Wp) // [4096][4096] bf16
{
    __shared__ __bf16 sm[2][2][2][8192];   // 128 KiB
    const int tid  = threadIdx.x;
    const int lane = tid & 63;
    const int wave = tid >> 6;
    const int wr = wave >> 2;
    const int wc = wave & 3;

    const int bid = blockIdx.x;
    const int cpx = gridDim.x >> 3;
    const int s   = (bid & 7) * cpx + (bid >> 3);
    const int mBase = (s >> 4) * 256;   // o
    const int nBase = (s & 15) * 256;   // i

    f32x4 acc[8][4] = {};
    __bf16* smp = &sm[0][0][0][0];
    run_pipeline(Ld, Rt, 256, 4, mBase, nBase, wave, lane, wr, wc, smp, acc);

    float* lsm = (float*)smp;            // [128][256] fp32 view
    const int cn = lane & 15;
    const int rg = (lane >> 4) * 4;

    #pragma unroll 1
    for (int h = 0; h < 2; ++h) {
        #pragma unroll
        for (int mf4 = 0; mf4 < 4; ++mf4) {
            const int mf = h * 4 + mf4;
            #pragma unroll
            for (int nf = 0; nf < 4; ++nf) {
                #pragma unroll
                for (int r = 0; r < 4; ++r) {
                    const int lrowi = wr * 64 + mf4 * 16 + rg + r;
                    const int col = (wc * 64 + nf * 16 + cn) ^ (((lrowi >> 2) & 1) << 4);
                    lsm[lrowi * 256 + col] = acc[mf][nf][r];
                }
            }
        }
        __syncthreads();
        #pragma unroll 2
        for (int it = 0; it < 8; ++it) {
            const int linear = it * 512 + tid;       // 0..4095
            const int lrowi  = linear >> 5;          // 0..127
            const int coff   = (linear & 31) * 8;
            const int grow = mBase + ((lrowi >> 6) * 128) + h * 64 + (lrowi & 63);
            const int gcol = nBase + coff;
            const int cswz = (coff * 4) ^ (((lrowi >> 2) & 1) << 6);
            const float* lp = (const float*)((const char*)lsm + (size_t)lrowi * 1024 + cswz);
            f32x4 lo = *(const f32x4*)lp;
            f32x4 hi = *(const f32x4*)(lp + 4);
            const float sc = qs[grow * 32 + (gcol >> 7)];
            const int4 qa = *(const int4*)&qv[(size_t)grow * 4096 + gcol];
            const int4 qb = *(const int4*)&qv[(size_t)grow * 4096 + gcol + 4];
            union { unsigned short u[8]; uint4 x; } w;
            w.u[0] = f2bf(qa.x * sc + lo[0]);
            w.u[1] = f2bf(qa.y * sc + lo[1]);
            w.u[2] = f2bf(qa.z * sc + lo[2]);
            w.u[3] = f2bf(qa.w * sc + lo[3]);
            w.u[4] = f2bf(qb.x * sc + hi[0]);
            w.u[5] = f2bf(qb.y * sc + hi[1]);
            w.u[6] = f2bf(qb.z * sc + hi[2]);
            w.u[7] = f2bf(qb.w * sc + hi[3]);
            *(uint4*)&Wp[(size_t)grow * 4096 + gcol] = w.x;
        }
        __syncthreads();
    }
}

// ---------------- main GEMM: out[T,DO] = xb @ Wp^T + bias ----------------
__global__ void __launch_bounds__(512, 2)
gemm256_kernel(const __bf16* __restrict__ A, const __bf16* __restrict__ B,
               int lda, int nt,
               const float* __restrict__ bias, float* __restrict__ out,
               int ldo, int gxlog2) {
    __shared__ __bf16 sm[2][2][2][8192];   // 128 KiB

    const int tid  = threadIdx.x;
    const int lane = tid & 63;
    const int wave = tid >> 6;
    const int wr = wave >> 2;
    const int wc = wave & 3;

    const int bid = blockIdx.x;
    const int cpx = gridDim.x >> 3;
    const int s   = (bid & 7) * cpx + (bid >> 3);
    const int bx  = s & ((1 << gxlog2) - 1);
    const int by  = s >> gxlog2;
    const int mBase = by * 256;
    const int nBase = bx * 256;

    f32x4 acc[8][4] = {};
    __bf16* smp = &sm[0][0][0][0];
    run_pipeline(A, B, lda, nt, mBase, nBase, wave, lane, wr, wc, smp, acc);

    // epilogue: C/D layout col = lane&15, row = (lane>>4)*4 + reg
    const int cn = lane & 15;
    const int rg = (lane >> 4) * 4;
    const int row0 = mBase + wr * 128 + rg;
    const int col0 = nBase + wc * 64 + cn;
    #pragma unroll
    for (int nf = 0; nf < 4; ++nf) {
        const int o = col0 + nf * 16;
        const float bv = bias[o];
        #pragma unroll
        for (int mf = 0; mf < 8; ++mf) {
            const int t0 = row0 + mf * 16;
            #pragma unroll
            for (int r = 0; r < 4; ++r)
                out[(size_t)(t0 + r) * ldo + o] = acc[mf][nf][r] + bv;
        }
    }
}

extern "C" void kernel_launch(void* const* d_in, const int* in_sizes, int n_in,
                              void* d_out, int out_size, void* d_ws, size_t ws_size,
                              hipStream_t stream) {
    const float* x    = (const float*)d_in[0];
    const int*   qv   = (const int*)d_in[1];
    const float* qs   = (const float*)d_in[2];
    const int*   lv   = (const int*)d_in[3];
    const float* ls   = (const float*)d_in[4];
    const int*   rv   = (const int*)d_in[5];
    const float* rs   = (const float*)d_in[6];
    const float* bias = (const float*)d_in[7];
    float* out = (float*)d_out;

    const int T = 8192, DI = 4096, DO = 4096;

    char* ws = (char*)d_ws;
    unsigned short* xb = (unsigned short*)(ws);                 // 8192x4096 bf16 = 64 MiB
    unsigned short* Wp = (unsigned short*)(ws + 67108864);      // 4096x4096 bf16 = 32 MiB
    unsigned short* Ld = (unsigned short*)(ws + 100663296);     // 4096x 256 bf16 =  2 MiB
    unsigned short* Rt = (unsigned short*)(ws + 102760448);     // 4096x 256 bf16 =  2 MiB

    {   // fused prep: cast x, dequant L, dequant+transpose R
        prep_kernel<<<17408, 256, 0, stream>>>(
            x, xb, lv, ls, Ld, rv, rs, Rt);
    }
    {   // Wp = Q*scale + Ld @ Rt^T   (fused dequant epilogue)
        lr_w_kernel<<<256, 512, 0, stream>>>(
            (const __bf16*)Ld, (const __bf16*)Rt, qv, qs, Wp);
    }
    {   // out = xb @ Wp^T + bias
        int nblocks = (DO / 256) * (T / 256);   // 512
        gemm256_kernel<<<nblocks, 512, 0, stream>>>(
            (const __bf16*)xb, (const __bf16*)Wp, DI, DI / 64,
            bias, out, DO, 4 /* log2(DO/256) */);
    }
}